// Round 8
// baseline (1077.711 us; speedup 1.0000x reference)
//
#include <hip/hip_runtime.h>
#include <hip/hip_bf16.h>
#include <hip/hip_fp16.h>

#define OC_N     2048
#define IC_N     2048
#define RC       6144      // rows = OC_N*3, cols = IC_N*3
#define OCSTRIDE 18432     // IC_N*9 floats per oc slice
#define UNSCALE  0.0000152587890625f   // 2^-16 cancels the fp8 256x encode scale per iter
#define NBLK     768       // persistent grid: 3 blocks/CU x 256 CUs
#define NITER    10
#define SLOT     16        // ints per barrier slot -> one 64B line per block

typedef float v2f __attribute__((ext_vector_type(2)));

__device__ __forceinline__ float wave_reduce(float x) {
#pragma unroll
    for (int off = 32; off > 0; off >>= 1) x += __shfl_down(x, off, 64);
    return x;
}

// sc0sc1 (cross-XCD coherent, L2-bypassing) scalar ops — used ONLY for
// result publication and barrier slots. Bulk reads are plain cached loads
// on fresh ping-pong buffers (no stale L2 copy can exist).
__device__ __forceinline__ void cstore(float* p, float x) {
    __hip_atomic_store(p, x, __ATOMIC_RELAXED, __HIP_MEMORY_SCOPE_AGENT);
}
__device__ __forceinline__ void cstore_i(int* p, int x) {
    __hip_atomic_store(p, x, __ATOMIC_RELAXED, __HIP_MEMORY_SCOPE_AGENT);
}
__device__ __forceinline__ int cload_i(const int* p) {
    return __hip_atomic_load(const_cast<int*>(p), __ATOMIC_RELAXED,
                             __HIP_MEMORY_SCOPE_AGENT);
}

// ---------------------------------------------------------------------------
// Wq[r][c] = fp8_e4m3(256 * conv[oc][ic][hh][ww]), r=oc*3+hh, c=ic*3+ww.
// Blocks 0..95 additionally zero the barrier slots (arrival+release, 24576
// ints); visible to power_iter via kernel-boundary release. 18432 blocks.
__global__ __launch_bounds__(256) void convert_q_kernel(
    const float* __restrict__ conv, unsigned char* __restrict__ Wq,
    int* __restrict__ barrier_mem)
{
    if (blockIdx.x < 2 * NBLK * SLOT / 256) {
        barrier_mem[blockIdx.x * 256 + threadIdx.x] = 0;
    }
    const int t  = blockIdx.x * 256 + threadIdx.x;
    const int o8 = t * 8;                       // < 2^26, fits int
    const int r  = o8 / RC;
    const int c0 = o8 % RC;
    const int oc = r / 3, hh = r % 3;
    const float* base = conv + (size_t)oc * OCSTRIDE + hh * 3;
    float f[8];
#pragma unroll
    for (int e = 0; e < 8; ++e) {
        const int c  = c0 + e;
        const int ic = c / 3, ww = c - 3 * ic;
        f[e] = base[ic * 9 + ww] * 256.0f;
    }
    int lo = __builtin_amdgcn_cvt_pk_fp8_f32(f[0], f[1], 0, false);
    lo     = __builtin_amdgcn_cvt_pk_fp8_f32(f[2], f[3], lo, true);
    int hi = __builtin_amdgcn_cvt_pk_fp8_f32(f[4], f[5], 0, false);
    hi     = __builtin_amdgcn_cvt_pk_fp8_f32(f[6], f[7], hi, true);
    *reinterpret_cast<uint2*>(Wq + o8) = make_uint2((unsigned)lo, (unsigned)hi);
}

// ---------------------------------------------------------------------------
// WqT[c][r] = Wq[r][c]  — 64x64 byte tiles via LDS. Grid (96, 96), 256 thr.
__global__ __launch_bounds__(256) void transpose_q_kernel(
    const unsigned char* __restrict__ Wq, unsigned char* __restrict__ WqT)
{
    __shared__ unsigned char tile[64][68];
    const int tid = threadIdx.x;
    const int tr  = blockIdx.x;          // row tile of Wq
    const int tc  = blockIdx.y;          // col tile of Wq

    const int r  = tid >> 2;
    const int cq = (tid & 3) * 16;
    const uint4 w = *reinterpret_cast<const uint4*>(
        Wq + (size_t)(tr * 64 + r) * RC + tc * 64 + cq);
    *reinterpret_cast<unsigned int*>(&tile[r][cq +  0]) = w.x;
    *reinterpret_cast<unsigned int*>(&tile[r][cq +  4]) = w.y;
    *reinterpret_cast<unsigned int*>(&tile[r][cq +  8]) = w.z;
    *reinterpret_cast<unsigned int*>(&tile[r][cq + 12]) = w.w;
    __syncthreads();

    const int orow = tid >> 2;
    const int ocq  = (tid & 3) * 16;
    unsigned int u32s[4];
#pragma unroll
    for (int wi = 0; wi < 4; ++wi) {
        const int ro = ocq + 4 * wi;
        u32s[wi] =  (unsigned int)tile[ro + 0][orow]
                 | ((unsigned int)tile[ro + 1][orow] << 8)
                 | ((unsigned int)tile[ro + 2][orow] << 16)
                 | ((unsigned int)tile[ro + 3][orow] << 24);
    }
    uint4 o = make_uint4(u32s[0], u32s[1], u32s[2], u32s[3]);
    *reinterpret_cast<uint4*>(WqT + (size_t)(tc * 64 + orow) * RC + tr * 64 + ocq) = o;
}

// ---------------------------------------------------------------------------
// 16-element fp8 dot: w holds 16 fp8, a..d hold the 16 matching f32 x-values.
__device__ __forceinline__ float dot16(uint4 w, float4 a, float4 b, float4 c, float4 d) {
    float acc = 0.f;
    v2f f;
    f = __builtin_amdgcn_cvt_pk_f32_fp8(w.x, false); acc += f.x * a.x + f.y * a.y;
    f = __builtin_amdgcn_cvt_pk_f32_fp8(w.x, true);  acc += f.x * a.z + f.y * a.w;
    f = __builtin_amdgcn_cvt_pk_f32_fp8(w.y, false); acc += f.x * b.x + f.y * b.y;
    f = __builtin_amdgcn_cvt_pk_f32_fp8(w.y, true);  acc += f.x * b.z + f.y * b.w;
    f = __builtin_amdgcn_cvt_pk_f32_fp8(w.z, false); acc += f.x * c.x + f.y * c.y;
    f = __builtin_amdgcn_cvt_pk_f32_fp8(w.z, true);  acc += f.x * c.z + f.y * c.w;
    f = __builtin_amdgcn_cvt_pk_f32_fp8(w.w, false); acc += f.x * d.x + f.y * d.y;
    f = __builtin_amdgcn_cvt_pk_f32_fp8(w.w, true);  acc += f.x * d.z + f.y * d.w;
    return acc;
}

// Stage x (6144 floats) into padded LDS with plain cached float4 loads.
// Padded layout: logical float4 g -> slot g + (g>>2): lane byte-stride 80 ->
// bank stride 20 -> conflict-free ds_read_b128 in the matvec. (round-2 body)
__device__ __forceinline__ void stage_x(const float* __restrict__ x,
                                        float4* __restrict__ x4, int tid) {
    const float4* s4 = reinterpret_cast<const float4*>(x);
#pragma unroll
    for (int k = 0; k < 6; ++k) {
        const int g = tid + 256 * k;              // logical float4 index
        x4[g + (g >> 2)] = s4[g];                 // padded slot
    }
}

// Two rows of W dot x (x in padded LDS). uint4 (16B) weight loads. (round-2)
__device__ __forceinline__ void matvec_rows2(
    const unsigned char* __restrict__ W, const float4* __restrict__ x4,
    int rbase, int lane, float* out0, float* out1)
{
    const unsigned char* w0 = W + (size_t)rbase * RC;
    float acc0 = 0.f, acc1 = 0.f;
#pragma unroll
    for (int i = 0; i < 6; ++i) {
        const int slot = i * 320 + lane * 5;      // padded float4 slot
        const float4 a = x4[slot + 0];
        const float4 b = x4[slot + 1];
        const float4 c = x4[slot + 2];
        const float4 d = x4[slot + 3];
        const uint4 wA = *reinterpret_cast<const uint4*>(w0 +      i * 1024 + lane * 16);
        const uint4 wB = *reinterpret_cast<const uint4*>(w0 + RC + i * 1024 + lane * 16);
        acc0 += dot16(wA, a, b, c, d);
        acc1 += dot16(wB, a, b, c, d);
    }
    *out0 = wave_reduce(acc0);
    *out1 = wave_reduce(acc1);
}

// ---------------------------------------------------------------------------
// Grid barrier v3 — no shared hot line.
// arrival[bid*SLOT] and release[bid*SLOT] each own a 64B line.
// Block 0's wave 0 polls the 768 spread arrival lines (12/lane), then writes
// 768 per-block release lines (12/lane). Every other block spins on its OWN
// release line only — zero line sharing, so the release store never queues
// behind a request storm (round-5's gen-line pathology).
// Ordering: __syncthreads() drains vmcnt before s_barrier, so all of this
// block's sc0sc1 data stores are at the coherence point before the arrival
// flag is published (proven in rounds 4/5, absmax 0.0).
__device__ __forceinline__ void grid_barrier(int* __restrict__ arrival,
                                             int* __restrict__ release,
                                             int bid, int tid, int g)
{
    __syncthreads();
    if (tid == 0) cstore_i(&arrival[bid * SLOT], g);
    if (bid == 0) {
        if (tid < 64) {
            const int base = tid * 12;            // 64 lanes x 12 = 768 blocks
            for (;;) {
                bool ok = true;
#pragma unroll
                for (int k = 0; k < 12; ++k)
                    ok &= (cload_i(&arrival[(base + k) * SLOT]) >= g);
                if (__all(ok)) break;
                __builtin_amdgcn_s_sleep(1);
            }
#pragma unroll
            for (int k = 0; k < 12; ++k)
                cstore_i(&release[(base + k) * SLOT], g);
        }
    } else if (tid == 0) {
        while (cload_i(&release[bid * SLOT]) < g)
            __builtin_amdgcn_s_sleep(1);
    }
    __syncthreads();
}

// ---------------------------------------------------------------------------
// All 10 power iterations PLUS the epilogue matvec (t = Wq*u10) in ONE
// persistent kernel: 21 phases, 20 barriers. 768 blocks x 256 thr;
// __launch_bounds__(256,3) -> 3 blocks/CU -> all 768 co-resident.
// Phase outputs go to FRESH ping-pong buffers (vbufs[it]/ubufs[it]) via
// sc0sc1 stores; readers use plain cached loads (round-5-proven scheme).
__global__ __launch_bounds__(256, 3) void power_iter_kernel(
    const unsigned char* __restrict__ Wq, const unsigned char* __restrict__ WqT,
    const float* __restrict__ u_in, float* __restrict__ vbufs,
    float* __restrict__ ubufs, int* __restrict__ barrier_mem)
{
    __shared__ float x_lds[7680];                 // 6144 + 1536 pad floats
    float4* x4 = reinterpret_cast<float4*>(x_lds);
    int* arrival = barrier_mem;
    int* release = barrier_mem + NBLK * SLOT;

    const int tid   = threadIdx.x;
    const int lane  = tid & 63;
    const int wid   = tid >> 6;
    const int bid   = blockIdx.x;
    const int rbase = bid * 8 + wid * 2;
    int g = 0;

    for (int it = 0; it <= NITER; ++it) {
        // ---- phase V: vbufs[it] = Wq * u_{it-1}  (it==NITER: t = Wq*u10) ----
        const float* src = (it == 0) ? u_in : (ubufs + (size_t)(it - 1) * RC);
        stage_x(src, x4, tid);
        __syncthreads();
        float a0, a1;
        matvec_rows2(Wq, x4, rbase, lane, &a0, &a1);
        float* vout = vbufs + (size_t)it * RC;
        if (lane == 0) { cstore(&vout[rbase], a0); cstore(&vout[rbase + 1], a1); }
        if (it == NITER) break;                   // epilogue phase: done
        ++g; grid_barrier(arrival, release, bid, tid, g);

        // ---- phase U: ubufs[it] = WqT * vbufs[it] * 2^-16 ----
        stage_x(vout, x4, tid);
        __syncthreads();
        matvec_rows2(WqT, x4, rbase, lane, &a0, &a1);
        float* uout = ubufs + (size_t)it * RC;
        if (lane == 0) {
            cstore(&uout[rbase],     a0 * UNSCALE);
            cstore(&uout[rbase + 1], a1 * UNSCALE);
        }
        ++g; grid_barrier(arrival, release, bid, tid, g);
    }
}

// ---------------------------------------------------------------------------
// sigma = 3 * dot(v10, t) / (256 * ||v10|| * ||u10||)
// t = Wq * u10 (unnormalized). Scale-free; fp8 epilogue error ~1e-3 << 0.18
// threshold (validated round 7, absmax 0.0).
__global__ __launch_bounds__(256) void final_kernel(
    const float* __restrict__ v, const float* __restrict__ t,
    const float* __restrict__ u, float* __restrict__ out)
{
    __shared__ float ssv[4];
    __shared__ float ssu[4];
    __shared__ float sdot[4];
    const int tid  = threadIdx.x;
    const int lane = tid & 63;
    const int wid  = tid >> 6;
    float sqv = 0.f, squ = 0.f, dot = 0.f;
#pragma unroll
    for (int k = 0; k < 24; ++k) {
        const float xv = v[tid + 256 * k];
        const float xt = t[tid + 256 * k];
        const float xu = u[tid + 256 * k];
        sqv += xv * xv;
        squ += xu * xu;
        dot += xv * xt;
    }
    sqv = wave_reduce(sqv);
    squ = wave_reduce(squ);
    dot = wave_reduce(dot);
    if (lane == 0) { ssv[wid] = sqv; ssu[wid] = squ; sdot[wid] = dot; }
    __syncthreads();
    if (tid == 0) {
        const float vs = ssv[0] + ssv[1] + ssv[2] + ssv[3];
        const float us = ssu[0] + ssu[1] + ssu[2] + ssu[3];
        const float dt = sdot[0] + sdot[1] + sdot[2] + sdot[3];
        out[0] = (3.0f / 256.0f) * dt * rsqrtf(vs) * rsqrtf(us);
    }
}

extern "C" void kernel_launch(void* const* d_in, const int* in_sizes, int n_in,
                              void* d_out, int out_size, void* d_ws, size_t ws_size,
                              hipStream_t stream)
{
    const float* conv = (const float*)d_in[0];   // [2048,2048,3,3] fp32
    const float* u_in = (const float*)d_in[1];   // [1,6144] fp32, unit norm
    float* out = (float*)d_out;

    // ws layout: Wq fp8[6144^2] | WqT fp8[6144^2] | vbufs[11][6144] |
    //            ubufs[10][6144] floats | barrier_mem[2*768*16] ints
    const size_t WQ_BYTES = (size_t)RC * RC;                     // 37.75 MB
    const size_t needed = 2 * WQ_BYTES
                        + (size_t)(2 * NITER + 1) * RC * sizeof(float)
                        + (size_t)2 * NBLK * SLOT * sizeof(int);
    if (ws_size < needed) return;

    unsigned char* Wq  = (unsigned char*)d_ws;
    unsigned char* WqT = Wq + WQ_BYTES;
    float* vbufs = (float*)(WqT + WQ_BYTES);
    float* ubufs = vbufs + (size_t)(NITER + 1) * RC;
    int*   bmem  = (int*)(ubufs + (size_t)NITER * RC);

    convert_q_kernel<<<RC * RC / 8 / 256, 256, 0, stream>>>(conv, Wq, bmem);
    transpose_q_kernel<<<dim3(RC / 64, RC / 64), 256, 0, stream>>>(Wq, WqT);
    power_iter_kernel<<<NBLK, 256, 0, stream>>>(Wq, WqT, u_in, vbufs, ubufs, bmem);

    // v10 = vbufs[9], t = vbufs[10], u10 = ubufs[9]
    final_kernel<<<1, 256, 0, stream>>>(
        vbufs + (size_t)(NITER - 1) * RC,
        vbufs + (size_t)NITER * RC,
        ubufs + (size_t)(NITER - 1) * RC, out);
}

// Round 9
// 405.414 us; speedup vs baseline: 2.6583x; 2.6583x over previous
//
#include <hip/hip_runtime.h>
#include <hip/hip_bf16.h>
#include <hip/hip_fp16.h>

#define OC_N     2048
#define IC_N     2048
#define RC       6144      // rows = OC_N*3, cols = IC_N*3
#define OCSTRIDE 18432     // IC_N*9 floats per oc slice
#define UNSCALE  0.0000152587890625f   // 2^-16 cancels the fp8 256x encode scale per iter

typedef float v2f __attribute__((ext_vector_type(2)));

__device__ __forceinline__ float wave_reduce(float x) {
#pragma unroll
    for (int off = 32; off > 0; off >>= 1) x += __shfl_down(x, off, 64);
    return x;
}

// ---------------------------------------------------------------------------
// Wq[r][c] = fp8_e4m3(256 * conv[oc][ic][hh][ww]), r=oc*3+hh, c=ic*3+ww.
// Thread writes 8 consecutive fp8 (8B store, coalesced). 18432 blocks.
__global__ __launch_bounds__(256) void convert_q_kernel(
    const float* __restrict__ conv, unsigned char* __restrict__ Wq)
{
    const int t  = blockIdx.x * 256 + threadIdx.x;
    const int o8 = t * 8;                       // < 2^26, fits int
    const int r  = o8 / RC;
    const int c0 = o8 % RC;
    const int oc = r / 3, hh = r % 3;
    const float* base = conv + (size_t)oc * OCSTRIDE + hh * 3;
    float f[8];
#pragma unroll
    for (int e = 0; e < 8; ++e) {
        const int c  = c0 + e;
        const int ic = c / 3, ww = c - 3 * ic;
        f[e] = base[ic * 9 + ww] * 256.0f;
    }
    int lo = __builtin_amdgcn_cvt_pk_fp8_f32(f[0], f[1], 0, false);
    lo     = __builtin_amdgcn_cvt_pk_fp8_f32(f[2], f[3], lo, true);
    int hi = __builtin_amdgcn_cvt_pk_fp8_f32(f[4], f[5], 0, false);
    hi     = __builtin_amdgcn_cvt_pk_fp8_f32(f[6], f[7], hi, true);
    *reinterpret_cast<uint2*>(Wq + o8) = make_uint2((unsigned)lo, (unsigned)hi);
}

// ---------------------------------------------------------------------------
// WqT[c][r] = Wq[r][c]  — 64x64 byte tiles via LDS. Grid (96, 96), 256 thr.
// LDS row stride 68 B keeps accesses to <=2-way bank conflicts.
__global__ __launch_bounds__(256) void transpose_q_kernel(
    const unsigned char* __restrict__ Wq, unsigned char* __restrict__ WqT)
{
    __shared__ unsigned char tile[64][68];
    const int tid = threadIdx.x;
    const int tr  = blockIdx.x;          // row tile of Wq
    const int tc  = blockIdx.y;          // col tile of Wq

    const int r  = tid >> 2;
    const int cq = (tid & 3) * 16;
    const uint4 w = *reinterpret_cast<const uint4*>(
        Wq + (size_t)(tr * 64 + r) * RC + tc * 64 + cq);
    *reinterpret_cast<unsigned int*>(&tile[r][cq +  0]) = w.x;
    *reinterpret_cast<unsigned int*>(&tile[r][cq +  4]) = w.y;
    *reinterpret_cast<unsigned int*>(&tile[r][cq +  8]) = w.z;
    *reinterpret_cast<unsigned int*>(&tile[r][cq + 12]) = w.w;
    __syncthreads();

    const int orow = tid >> 2;
    const int ocq  = (tid & 3) * 16;
    unsigned int u32s[4];
#pragma unroll
    for (int wi = 0; wi < 4; ++wi) {
        const int ro = ocq + 4 * wi;
        u32s[wi] =  (unsigned int)tile[ro + 0][orow]
                 | ((unsigned int)tile[ro + 1][orow] << 8)
                 | ((unsigned int)tile[ro + 2][orow] << 16)
                 | ((unsigned int)tile[ro + 3][orow] << 24);
    }
    uint4 o = make_uint4(u32s[0], u32s[1], u32s[2], u32s[3]);
    *reinterpret_cast<uint4*>(WqT + (size_t)(tc * 64 + orow) * RC + tr * 64 + ocq) = o;
}

// ---------------------------------------------------------------------------
// 16-element fp8 dot: w holds 16 fp8, a..d hold the 16 matching f32 x-values.
__device__ __forceinline__ float dot16(uint4 w, float4 a, float4 b, float4 c, float4 d) {
    float acc = 0.f;
    v2f f;
    f = __builtin_amdgcn_cvt_pk_f32_fp8(w.x, false); acc += f.x * a.x + f.y * a.y;
    f = __builtin_amdgcn_cvt_pk_f32_fp8(w.x, true);  acc += f.x * a.z + f.y * a.w;
    f = __builtin_amdgcn_cvt_pk_f32_fp8(w.y, false); acc += f.x * b.x + f.y * b.y;
    f = __builtin_amdgcn_cvt_pk_f32_fp8(w.y, true);  acc += f.x * b.z + f.y * b.w;
    f = __builtin_amdgcn_cvt_pk_f32_fp8(w.z, false); acc += f.x * c.x + f.y * c.y;
    f = __builtin_amdgcn_cvt_pk_f32_fp8(w.z, true);  acc += f.x * c.z + f.y * c.w;
    f = __builtin_amdgcn_cvt_pk_f32_fp8(w.w, false); acc += f.x * d.x + f.y * d.y;
    f = __builtin_amdgcn_cvt_pk_f32_fp8(w.w, true);  acc += f.x * d.z + f.y * d.w;
    return acc;
}

// Stage x (6144 floats) into padded LDS with cached float4 loads.
// Padded layout: logical float4 g -> slot g + (g>>2): lane byte-stride 80 ->
// bank stride 20 -> conflict-free ds_read_b128 in the matvec.
__device__ __forceinline__ void stage_x(const float* __restrict__ x,
                                        float4* __restrict__ x4, int tid) {
    const float4* s4 = reinterpret_cast<const float4*>(x);
#pragma unroll
    for (int k = 0; k < 6; ++k) {
        const int g = tid + 256 * k;              // logical float4 index
        x4[g + (g >> 2)] = s4[g];                 // padded slot
    }
}

// Two rows of W dot x (x in padded LDS). uint4 (16B) weight loads.
__device__ __forceinline__ void matvec_rows2(
    const unsigned char* __restrict__ W, const float4* __restrict__ x4,
    int rbase, int lane, float* out0, float* out1)
{
    const unsigned char* w0 = W + (size_t)rbase * RC;
    float acc0 = 0.f, acc1 = 0.f;
#pragma unroll
    for (int i = 0; i < 6; ++i) {
        const int slot = i * 320 + lane * 5;      // padded float4 slot
        const float4 a = x4[slot + 0];
        const float4 b = x4[slot + 1];
        const float4 c = x4[slot + 2];
        const float4 d = x4[slot + 3];
        const uint4 wA = *reinterpret_cast<const uint4*>(w0 +      i * 1024 + lane * 16);
        const uint4 wB = *reinterpret_cast<const uint4*>(w0 + RC + i * 1024 + lane * 16);
        acc0 += dot16(wA, a, b, c, d);
        acc1 += dot16(wB, a, b, c, d);
    }
    *out0 = wave_reduce(acc0);
    *out1 = wave_reduce(acc1);
}

// ---------------------------------------------------------------------------
// y[r] = scale * sum_c W[r][c] * x[c].  768 blocks x 256 thr (3/CU exact).
// Block = 8 rows, wave = 2 rows.
__global__ __launch_bounds__(256) void matvec_q_kernel(
    const unsigned char* __restrict__ W, const float* __restrict__ x,
    float* __restrict__ y, float scale)
{
    __shared__ float x_lds[7680];                 // 6144 + 1536 pad floats
    float4* x4 = reinterpret_cast<float4*>(x_lds);

    const int tid  = threadIdx.x;
    const int lane = tid & 63;
    const int wid  = tid >> 6;

    stage_x(x, x4, tid);
    __syncthreads();

    const int rbase = blockIdx.x * 8 + wid * 2;
    float a0, a1;
    matvec_rows2(W, x4, rbase, lane, &a0, &a1);
    if (lane == 0) { y[rbase] = a0 * scale; y[rbase + 1] = a1 * scale; }
}

// ---------------------------------------------------------------------------
// sigma = 3 * dot(v10, t) / (256 * ||v10|| * ||u10||),  t = Wq * u10.
// Scale-free; fp8 epilogue error ~1e-3 << 0.18 threshold (validated round 7).
__global__ __launch_bounds__(256) void final_kernel(
    const float* __restrict__ v, const float* __restrict__ t,
    const float* __restrict__ u, float* __restrict__ out)
{
    __shared__ float ssv[4];
    __shared__ float ssu[4];
    __shared__ float sdot[4];
    const int tid  = threadIdx.x;
    const int lane = tid & 63;
    const int wid  = tid >> 6;
    float sqv = 0.f, squ = 0.f, dot = 0.f;
#pragma unroll
    for (int k = 0; k < 24; ++k) {
        const float xv = v[tid + 256 * k];
        const float xt = t[tid + 256 * k];
        const float xu = u[tid + 256 * k];
        sqv += xv * xv;
        squ += xu * xu;
        dot += xv * xt;
    }
    sqv = wave_reduce(sqv);
    squ = wave_reduce(squ);
    dot = wave_reduce(dot);
    if (lane == 0) { ssv[wid] = sqv; ssu[wid] = squ; sdot[wid] = dot; }
    __syncthreads();
    if (tid == 0) {
        const float vs = ssv[0] + ssv[1] + ssv[2] + ssv[3];
        const float us = ssu[0] + ssu[1] + ssu[2] + ssu[3];
        const float dt = sdot[0] + sdot[1] + sdot[2] + sdot[3];
        out[0] = (3.0f / 256.0f) * dt * rsqrtf(vs) * rsqrtf(us);
    }
}

extern "C" void kernel_launch(void* const* d_in, const int* in_sizes, int n_in,
                              void* d_out, int out_size, void* d_ws, size_t ws_size,
                              hipStream_t stream)
{
    const float* conv = (const float*)d_in[0];   // [2048,2048,3,3] fp32
    const float* u_in = (const float*)d_in[1];   // [1,6144] fp32, unit norm
    float* out = (float*)d_out;

    // ws layout: Wq fp8[6144^2] | WqT fp8[6144^2] | v_vec[6144] | u_vec[6144]
    //            | t_vec[6144] floats
    const size_t WQ_BYTES = (size_t)RC * RC;                     // 37.75 MB
    const size_t needed = 2 * WQ_BYTES + (size_t)3 * RC * sizeof(float);
    if (ws_size < needed) return;

    unsigned char* Wq  = (unsigned char*)d_ws;
    unsigned char* WqT = Wq + WQ_BYTES;
    float* v_vec = (float*)(WqT + WQ_BYTES);
    float* u_vec = v_vec + RC;
    float* t_vec = u_vec + RC;

    convert_q_kernel<<<RC * RC / 8 / 256, 256, 0, stream>>>(conv, Wq);
    transpose_q_kernel<<<dim3(RC / 64, RC / 64), 256, 0, stream>>>(Wq, WqT);

    for (int i = 0; i < 10; ++i) {
        matvec_q_kernel<<<RC / 8, 256, 0, stream>>>(
            Wq, (i == 0) ? u_in : u_vec, v_vec, 1.0f);
        matvec_q_kernel<<<RC / 8, 256, 0, stream>>>(
            WqT, v_vec, u_vec, UNSCALE);
    }

    // fp8 epilogue: t = Wq * u10, then sigma from three reductions
    matvec_q_kernel<<<RC / 8, 256, 0, stream>>>(Wq, u_vec, t_vec, 1.0f);
    final_kernel<<<1, 256, 0, stream>>>(v_vec, t_vec, u_vec, out);
}

// Round 10
// 394.197 us; speedup vs baseline: 2.7339x; 1.0285x over previous
//
#include <hip/hip_runtime.h>
#include <hip/hip_bf16.h>
#include <hip/hip_fp16.h>

#define OC_N     2048
#define IC_N     2048
#define RC       6144      // rows = OC_N*3, cols = IC_N*3
#define OCSTRIDE 18432     // IC_N*9 floats per oc slice
#define UNSCALE  0.0000152587890625f   // 2^-16 cancels the fp8 256x encode scale per iter

typedef float v2f __attribute__((ext_vector_type(2)));

__device__ __forceinline__ float wave_reduce(float x) {
#pragma unroll
    for (int off = 32; off > 0; off >>= 1) x += __shfl_down(x, off, 64);
    return x;
}

// ---------------------------------------------------------------------------
// Fused quantize + transpose. Grid (96,96), 256 thr. Per block: one 64x64
// tile of Wq[r][c] = fp8_e4m3(256*conv[oc][ic][hh][ww]) (r=oc*3+hh, c=ic*3+ww)
// is built in LDS, then written row-major to Wq AND column-major to WqT.
// Source gather (stride-9 within ~800B windows) matches the proven convert
// kernel's pattern; both write phases are byte-identical to the proven
// transpose kernel. Saves the 37.75 MB transpose re-read + one dispatch.
__global__ __launch_bounds__(256) void convert_both_kernel(
    const float* __restrict__ conv, unsigned char* __restrict__ Wq,
    unsigned char* __restrict__ WqT)
{
    __shared__ unsigned char tile[64][68];   // stride 68: <=2-way LDS conflicts
    const int tid = threadIdx.x;
    const int tr  = blockIdx.x;              // row tile
    const int tc  = blockIdx.y;              // col tile

    // ---- phase 1: gather fp32, quantize, fill LDS tile ----
    {
        const int rl = tid >> 2;             // 0..63 local row
        const int cq = (tid & 3) * 16;       // 16 cols per thread
        const int r  = tr * 64 + rl;
        const int oc = r / 3, hh = r % 3;
        const float* base = conv + (size_t)oc * OCSTRIDE + hh * 3;
        float f[16];
#pragma unroll
        for (int j = 0; j < 16; ++j) {
            const int c  = tc * 64 + cq + j;
            const int ic = c / 3, ww = c - 3 * ic;
            f[j] = base[ic * 9 + ww] * 256.0f;
        }
        unsigned int w32[4];
#pragma unroll
        for (int q = 0; q < 4; ++q) {
            int v = __builtin_amdgcn_cvt_pk_fp8_f32(f[4*q+0], f[4*q+1], 0, false);
            v     = __builtin_amdgcn_cvt_pk_fp8_f32(f[4*q+2], f[4*q+3], v, true);
            w32[q] = (unsigned)v;
        }
#pragma unroll
        for (int q = 0; q < 4; ++q)
            *reinterpret_cast<unsigned int*>(&tile[rl][cq + 4*q]) = w32[q];
    }
    __syncthreads();

    // ---- phase 2a: row-major tile -> Wq (proven transpose-load pattern) ----
    {
        const int rl = tid >> 2;
        const int cq = (tid & 3) * 16;
        uint4 o;
        o.x = *reinterpret_cast<const unsigned int*>(&tile[rl][cq +  0]);
        o.y = *reinterpret_cast<const unsigned int*>(&tile[rl][cq +  4]);
        o.z = *reinterpret_cast<const unsigned int*>(&tile[rl][cq +  8]);
        o.w = *reinterpret_cast<const unsigned int*>(&tile[rl][cq + 12]);
        *reinterpret_cast<uint4*>(
            Wq + (size_t)(tr * 64 + rl) * RC + tc * 64 + cq) = o;
    }

    // ---- phase 2b: transposed gather -> WqT (proven transpose pattern) ----
    {
        const int orow = tid >> 2;
        const int ocq  = (tid & 3) * 16;
        unsigned int u32s[4];
#pragma unroll
        for (int wi = 0; wi < 4; ++wi) {
            const int ro = ocq + 4 * wi;
            u32s[wi] =  (unsigned int)tile[ro + 0][orow]
                     | ((unsigned int)tile[ro + 1][orow] << 8)
                     | ((unsigned int)tile[ro + 2][orow] << 16)
                     | ((unsigned int)tile[ro + 3][orow] << 24);
        }
        uint4 o = make_uint4(u32s[0], u32s[1], u32s[2], u32s[3]);
        *reinterpret_cast<uint4*>(
            WqT + (size_t)(tc * 64 + orow) * RC + tr * 64 + ocq) = o;
    }
}

// ---------------------------------------------------------------------------
// 16-element fp8 dot: w holds 16 fp8, a..d hold the 16 matching f32 x-values.
__device__ __forceinline__ float dot16(uint4 w, float4 a, float4 b, float4 c, float4 d) {
    float acc = 0.f;
    v2f f;
    f = __builtin_amdgcn_cvt_pk_f32_fp8(w.x, false); acc += f.x * a.x + f.y * a.y;
    f = __builtin_amdgcn_cvt_pk_f32_fp8(w.x, true);  acc += f.x * a.z + f.y * a.w;
    f = __builtin_amdgcn_cvt_pk_f32_fp8(w.y, false); acc += f.x * b.x + f.y * b.y;
    f = __builtin_amdgcn_cvt_pk_f32_fp8(w.y, true);  acc += f.x * b.z + f.y * b.w;
    f = __builtin_amdgcn_cvt_pk_f32_fp8(w.z, false); acc += f.x * c.x + f.y * c.y;
    f = __builtin_amdgcn_cvt_pk_f32_fp8(w.z, true);  acc += f.x * c.z + f.y * c.w;
    f = __builtin_amdgcn_cvt_pk_f32_fp8(w.w, false); acc += f.x * d.x + f.y * d.y;
    f = __builtin_amdgcn_cvt_pk_f32_fp8(w.w, true);  acc += f.x * d.z + f.y * d.w;
    return acc;
}

// Stage x (6144 floats) into padded LDS with cached float4 loads.
// Padded layout: logical float4 g -> slot g + (g>>2): lane byte-stride 80 ->
// bank stride 20 -> conflict-free ds_read_b128 in the matvec.
__device__ __forceinline__ void stage_x(const float* __restrict__ x,
                                        float4* __restrict__ x4, int tid) {
    const float4* s4 = reinterpret_cast<const float4*>(x);
#pragma unroll
    for (int k = 0; k < 6; ++k) {
        const int g = tid + 256 * k;              // logical float4 index
        x4[g + (g >> 2)] = s4[g];                 // padded slot
    }
}

// Two rows of W dot x (x in padded LDS). uint4 (16B) weight loads.
__device__ __forceinline__ void matvec_rows2(
    const unsigned char* __restrict__ W, const float4* __restrict__ x4,
    int rbase, int lane, float* out0, float* out1)
{
    const unsigned char* w0 = W + (size_t)rbase * RC;
    float acc0 = 0.f, acc1 = 0.f;
#pragma unroll
    for (int i = 0; i < 6; ++i) {
        const int slot = i * 320 + lane * 5;      // padded float4 slot
        const float4 a = x4[slot + 0];
        const float4 b = x4[slot + 1];
        const float4 c = x4[slot + 2];
        const float4 d = x4[slot + 3];
        const uint4 wA = *reinterpret_cast<const uint4*>(w0 +      i * 1024 + lane * 16);
        const uint4 wB = *reinterpret_cast<const uint4*>(w0 + RC + i * 1024 + lane * 16);
        acc0 += dot16(wA, a, b, c, d);
        acc1 += dot16(wB, a, b, c, d);
    }
    *out0 = wave_reduce(acc0);
    *out1 = wave_reduce(acc1);
}

// ---------------------------------------------------------------------------
// y[r] = scale * sum_c W[r][c] * x[c].  768 blocks x 256 thr (3/CU exact).
// Block = 8 rows, wave = 2 rows.  (round-9 proven body, unchanged)
__global__ __launch_bounds__(256) void matvec_q_kernel(
    const unsigned char* __restrict__ W, const float* __restrict__ x,
    float* __restrict__ y, float scale)
{
    __shared__ float x_lds[7680];                 // 6144 + 1536 pad floats
    float4* x4 = reinterpret_cast<float4*>(x_lds);

    const int tid  = threadIdx.x;
    const int lane = tid & 63;
    const int wid  = tid >> 6;

    stage_x(x, x4, tid);
    __syncthreads();

    const int rbase = blockIdx.x * 8 + wid * 2;
    float a0, a1;
    matvec_rows2(W, x4, rbase, lane, &a0, &a1);
    if (lane == 0) { y[rbase] = a0 * scale; y[rbase + 1] = a1 * scale; }
}

// ---------------------------------------------------------------------------
// sigma = 768 * ||u10|| / ||v10||.
// Derivation: u10 = UNSCALE * WqT v10, so v10' Wq u10 = ||u10||^2 / UNSCALE,
// and sigma = (3/256) * (v10' Wq u10)/(||v10|| ||u10||)
//           = (3/(256*UNSCALE)) * ||u10||/||v10|| = 768 * ||u10||/||v10||.
// Exactly equal to round-9's epilogue (absmax 0.0) with no extra matvec.
__global__ __launch_bounds__(256) void final_kernel(
    const float* __restrict__ v, const float* __restrict__ u,
    float* __restrict__ out)
{
    __shared__ float ssv[4];
    __shared__ float ssu[4];
    const int tid  = threadIdx.x;
    const int lane = tid & 63;
    const int wid  = tid >> 6;
    float sqv = 0.f, squ = 0.f;
#pragma unroll
    for (int k = 0; k < 24; ++k) {
        const float xv = v[tid + 256 * k];
        const float xu = u[tid + 256 * k];
        sqv += xv * xv;
        squ += xu * xu;
    }
    sqv = wave_reduce(sqv);
    squ = wave_reduce(squ);
    if (lane == 0) { ssv[wid] = sqv; ssu[wid] = squ; }
    __syncthreads();
    if (tid == 0) {
        const float vs = ssv[0] + ssv[1] + ssv[2] + ssv[3];
        const float us = ssu[0] + ssu[1] + ssu[2] + ssu[3];
        out[0] = 768.0f * sqrtf(us / vs);
    }
}

extern "C" void kernel_launch(void* const* d_in, const int* in_sizes, int n_in,
                              void* d_out, int out_size, void* d_ws, size_t ws_size,
                              hipStream_t stream)
{
    const float* conv = (const float*)d_in[0];   // [2048,2048,3,3] fp32
    const float* u_in = (const float*)d_in[1];   // [1,6144] fp32, unit norm
    float* out = (float*)d_out;

    // ws layout: Wq fp8[6144^2] | WqT fp8[6144^2] | v_vec[6144] | u_vec[6144]
    const size_t WQ_BYTES = (size_t)RC * RC;                     // 37.75 MB
    const size_t needed = 2 * WQ_BYTES + (size_t)2 * RC * sizeof(float);
    if (ws_size < needed) return;

    unsigned char* Wq  = (unsigned char*)d_ws;
    unsigned char* WqT = Wq + WQ_BYTES;
    float* v_vec = (float*)(WqT + WQ_BYTES);
    float* u_vec = v_vec + RC;

    convert_both_kernel<<<dim3(RC / 64, RC / 64), 256, 0, stream>>>(conv, Wq, WqT);

    for (int i = 0; i < 10; ++i) {
        matvec_q_kernel<<<RC / 8, 256, 0, stream>>>(
            Wq, (i == 0) ? u_in : u_vec, v_vec, 1.0f);
        matvec_q_kernel<<<RC / 8, 256, 0, stream>>>(
            WqT, v_vec, u_vec, UNSCALE);
    }

    // sigma = 768 * ||u10|| / ||v10||  (algebraic epilogue, no extra matvec)
    final_kernel<<<1, 256, 0, stream>>>(v_vec, u_vec, out);
}